// Round 3
// baseline (682.849 us; speedup 1.0000x reference)
//
#include <hip/hip_runtime.h>
#include <math.h>

// Problem constants (from reference setup_inputs): n=16, b=4, t=2048, h=1024
#define H     1024
#define NBLK  16
#define BT    8192                 // b * t
#define ROUTED_SIZE (BT * H)       // 8,388,608 floats
#define SCALE_INV (1.0f / 32.0f)   // 1 / (sqrt(1024) * BASE_TAU)

typedef float v4f __attribute__((ext_vector_type(4)));

// ---------------------------------------------------------------------------
// Pre-kernel: qb[n] = sum_h w_query[pos][h] * key_pos_bias[n][h]  (n = 0..15)
// ---------------------------------------------------------------------------
__global__ __launch_bounds__(1024) void qb_kernel(
    const float* __restrict__ w_query,
    const float* __restrict__ key_pos_bias,
    const int*   __restrict__ pos_p,
    float*       __restrict__ qb)
{
    const int n    = threadIdx.x >> 6;   // wave id = history slot
    const int lane = threadIdx.x & 63;
    const int pos  = *pos_p;

    const float* q = w_query      + (size_t)pos * H;
    const float* b = key_pos_bias + (size_t)n   * H;

    float s = 0.0f;
#pragma unroll
    for (int j = 0; j < 4; ++j) {
        const int h = lane * 16 + j * 4;
        const float4 qv = *(const float4*)(q + h);
        const float4 bv = *(const float4*)(b + h);
        s += qv.x * bv.x + qv.y * bv.y + qv.z * bv.z + qv.w * bv.w;
    }
#pragma unroll
    for (int off = 32; off; off >>= 1) s += __shfl_xor(s, off, 64);
    if (lane == 0) qb[n] = s;
}

// ---------------------------------------------------------------------------
// Main kernel v4: 1024-thread block per (b,t) column.
//   thread (g,c): g = tid>>8 owns planes 4g..4g+3, c = tid&255 owns h = 4c..4c+3
//   - per-thread payload v4f v[4] = 16 VGPRs (was 64) -> __launch_bounds__(1024,8)
//     caps VGPR at 64 -> 32 waves/CU (2x v3's occupancy)
//   - score reduce: wave w reduces plane w (16 waves <-> 16 planes, parallel)
//   - routed: per-thread 4-plane partial -> LDS combine of 4 v4f per h-column
//   - nontemporal only on the routed store (streamed, never re-read by us);
//     loads are plain (A/B vs v3's nt loads)
// values is read from HBM exactly once.
// ---------------------------------------------------------------------------
__global__ __launch_bounds__(1024, 8) void block_attn_res_kernel(
    const float* __restrict__ values,   // [16, 4, 2048, 1024]
    const float* __restrict__ w_query,  // [24, 1024]
    const int*   __restrict__ pos_p,    // scalar (16)
    const float* __restrict__ qb,       // [16] precomputed q·bias
    float*       __restrict__ out)      // routed [4,2048,1024] ++ alpha [4,2048,16]
{
    const int bt  = blockIdx.x;        // 0..8191
    const int tid = threadIdx.x;       // 0..1023
    const int c   = tid & 255;         // h-column group
    const int g   = tid >> 8;          // 0..3: plane group (wave-uniform)
    const int h0  = c << 2;

    __shared__ float2 pv[NBLK][256];   // 32 KiB: per-plane (ss,qv) partials
    __shared__ v4f    rp[4][256];      // 16 KiB: routed partials per plane-group
    __shared__ float  scores[NBLK];

    const int pos = *pos_p;
    const v4f q = *(const v4f*)(w_query + (size_t)pos * H + h0);

    // ---- one-shot HBM read: 4 planes x 16 B per thread ----
    v4f v[4];
    const float* vbase = values + (size_t)bt * H + h0 + (size_t)g * 4 * BT * H;
#pragma unroll
    for (int i = 0; i < 4; ++i)
        v[i] = *(const v4f*)(vbase + (size_t)i * BT * H);

    // ---- per-thread (ss, qv) partials -> LDS ----
#pragma unroll
    for (int i = 0; i < 4; ++i) {
        const v4f x  = v[i];
        const v4f xx = x * x;
        const v4f qx = q * x;
        pv[g * 4 + i][c] = make_float2((xx[0] + xx[1]) + (xx[2] + xx[3]),
                                       (qx[0] + qx[1]) + (qx[2] + qx[3]));
    }
    __syncthreads();

    // ---- wave w reduces plane w: 4 ds_read_b64 + 6-level shuffle ----
    {
        const int n2   = tid >> 6;     // 0..15 == wave id
        const int lane = tid & 63;
        const float2 p0 = pv[n2][lane];
        const float2 p1 = pv[n2][lane + 64];
        const float2 p2 = pv[n2][lane + 128];
        const float2 p3 = pv[n2][lane + 192];
        float ss = (p0.x + p1.x) + (p2.x + p3.x);
        float qv = (p0.y + p1.y) + (p2.y + p3.y);
#pragma unroll
        for (int off = 32; off; off >>= 1) {
            ss += __shfl_xor(ss, off, 64);
            qv += __shfl_xor(qv, off, 64);
        }
        if (lane == 0) {
            const float inv = rsqrtf(ss * (1.0f / (float)H) + 1e-6f);
            scores[n2] = (inv * qv + qb[n2]) * SCALE_INV;
        }
    }
    __syncthreads();

    // ---- redundant per-thread softmax over the 16 broadcast scores ----
    float m = -3.402823466e38f;
#pragma unroll
    for (int n = 0; n < NBLK; ++n) m = fmaxf(m, scores[n]);

    float ag[4];                       // alpha numerators for this thread's planes
    float sum = 0.0f;
#pragma unroll
    for (int n = 0; n < NBLK; ++n) {
        const float e = __expf(scores[n] - m);
        sum += e;
        if ((n >> 2) == g) ag[n & 3] = e;   // wave-uniform predicate, static index
    }
    const float rs = 1.0f / sum;

    // ---- routed partial over this thread's 4 planes -> LDS combine ----
    v4f acc = {0.0f, 0.0f, 0.0f, 0.0f};
#pragma unroll
    for (int i = 0; i < 4; ++i) acc += (ag[i] * rs) * v[i];
    rp[g][c] = acc;
    __syncthreads();

    if (g == 0) {
        const v4f r = (rp[0][c] + rp[1][c]) + (rp[2][c] + rp[3][c]);
        __builtin_nontemporal_store(r, (v4f*)(out + (size_t)bt * H + h0));
    }

    // ---- alpha_bth[b,t,n]: dynamic index into LDS scores, not registers ----
    if (tid < NBLK)
        out[(size_t)ROUTED_SIZE + (size_t)bt * NBLK + tid]
            = __expf(scores[tid] - m) * rs;
}

extern "C" void kernel_launch(void* const* d_in, const int* in_sizes, int n_in,
                              void* d_out, int out_size, void* d_ws, size_t ws_size,
                              hipStream_t stream) {
    const float* values       = (const float*)d_in[0];
    const float* w_query      = (const float*)d_in[1];
    const float* key_pos_bias = (const float*)d_in[2];
    const int*   position     = (const int*)d_in[3];
    float*       out          = (float*)d_out;
    float*       qb           = (float*)d_ws;   // 16 floats of scratch

    hipLaunchKernelGGL(qb_kernel, dim3(1), dim3(1024), 0, stream,
                       w_query, key_pos_bias, position, qb);
    hipLaunchKernelGGL(block_attn_res_kernel, dim3(BT), dim3(1024), 0, stream,
                       values, w_query, position, qb, out);
}